// Round 1
// baseline (44674.200 us; speedup 1.0000x reference)
//
#include <hip/hip_runtime.h>

// GIN: 5 layers, DIM=10, F_IN=64. Key identity: (x+agg)@W1 = x@W1 + segsum((x@W1)[src]).
// So we keep y = x@W1 (padded to PAD floats/row for 64B line containment) and
// aggregate in 10-dim space. x_i is never materialized.

// ---------------- Layer-1: y = h @ W1_1   (h:[N,64], W1:[64,10]) ----------------
template<int PAD>
__global__ void k1_hw1(const float* __restrict__ h, const float* __restrict__ W1,
                       float* __restrict__ y, int N) {
    __shared__ float sW[640];
    for (int i = threadIdx.x; i < 640; i += blockDim.x) sW[i] = W1[i];
    __syncthreads();
    int n = blockIdx.x * blockDim.x + threadIdx.x;
    if (n >= N) return;
    const float* hr = h + (size_t)n * 64;
    float acc[10];
#pragma unroll
    for (int j = 0; j < 10; j++) acc[j] = 0.f;
#pragma unroll 4
    for (int k = 0; k < 64; k += 4) {
        float4 hv = *(const float4*)(hr + k);
#pragma unroll
        for (int j = 0; j < 10; j++) {
            acc[j] += hv.x * sW[(k + 0) * 10 + j];
            acc[j] += hv.y * sW[(k + 1) * 10 + j];
            acc[j] += hv.z * sW[(k + 2) * 10 + j];
            acc[j] += hv.w * sW[(k + 3) * 10 + j];
        }
    }
    float* yr = y + (size_t)n * PAD;
#pragma unroll
    for (int j = 0; j < 10; j++) yr[j] = acc[j];
}

// ---------------- Edge aggregation: agg[dst] += y[src] ----------------
template<int PAD>
__global__ void k2_edge(const int* __restrict__ src, const int* __restrict__ dst,
                        const float* __restrict__ y, float* __restrict__ agg, int E) {
    int e = blockIdx.x * blockDim.x + threadIdx.x;
    if (e >= E) return;
    size_t s = (size_t)src[e] * PAD;
    size_t d = (size_t)dst[e] * PAD;
    float4 a = *(const float4*)(y + s);
    float4 b = *(const float4*)(y + s + 4);
    float2 c = *(const float2*)(y + s + 8);
    float* ag = agg + d;
    unsafeAtomicAdd(ag + 0, a.x); unsafeAtomicAdd(ag + 1, a.y);
    unsafeAtomicAdd(ag + 2, a.z); unsafeAtomicAdd(ag + 3, a.w);
    unsafeAtomicAdd(ag + 4, b.x); unsafeAtomicAdd(ag + 5, b.y);
    unsafeAtomicAdd(ag + 6, b.z); unsafeAtomicAdd(ag + 7, b.w);
    unsafeAtomicAdd(ag + 8, c.x); unsafeAtomicAdd(ag + 9, c.y);
}

// ------- Node update: z=relu(y+agg+b1); x=relu(z@W2+b2); p=x.l (-> gacc);
//         y := x@W1_next (in place); agg := 0 -------
template<int PAD>
__global__ void k3_node(float* __restrict__ y, float* __restrict__ agg,
                        const float* __restrict__ b1, const float* __restrict__ W2,
                        const float* __restrict__ b2, const float* __restrict__ l,
                        const float* __restrict__ W1n,
                        const int* __restrict__ node_graph, float* __restrict__ gacc,
                        int N, int last) {
    __shared__ float sW2[100], sW1[100], sb1[10], sb2[10], sl[10];
    int t = threadIdx.x;
    if (t < 100) sW2[t] = W2[t];
    if (!last && t >= 128 && t < 228) sW1[t - 128] = W1n[t - 128];
    if (t < 10) { sb1[t] = b1[t]; sb2[t] = b2[t]; sl[t] = l[t]; }
    __syncthreads();
    int n = blockIdx.x * blockDim.x + t;
    bool valid = n < N;
    int nc = valid ? n : (N - 1);
    float* yr = y + (size_t)nc * PAD;
    float* ar = agg + (size_t)nc * PAD;
    float z[10], x[10];
#pragma unroll
    for (int j = 0; j < 10; j++) {
        float v = yr[j] + ar[j] + sb1[j];
        z[j] = v > 0.f ? v : 0.f;
    }
    if (valid) {
#pragma unroll
        for (int j = 0; j < 10; j++) ar[j] = 0.f;
    }
#pragma unroll
    for (int j = 0; j < 10; j++) {
        float v = sb2[j];
#pragma unroll
        for (int k = 0; k < 10; k++) v += z[k] * sW2[k * 10 + j];
        x[j] = v > 0.f ? v : 0.f;
    }
    float p = 0.f;
#pragma unroll
    for (int j = 0; j < 10; j++) p += x[j] * sl[j];
    if (!valid) p = 0.f;
    int g = node_graph[nc];

    // node_graph is sorted -> most waves see a single graph id: reduce then 1 atomic
    int g0 = __shfl(g, 0);
    if (__all(g == g0)) {
#pragma unroll
        for (int off = 32; off > 0; off >>= 1) p += __shfl_down(p, off);
        if ((t & 63) == 0) unsafeAtomicAdd(&gacc[g0], p);
    } else {
        if (valid) unsafeAtomicAdd(&gacc[g], p);
    }

    if (!last && valid) {
        float yn[10];
#pragma unroll
        for (int j = 0; j < 10; j++) {
            float v = 0.f;
#pragma unroll
            for (int k = 0; k < 10; k++) v += x[k] * sW1[k * 10 + j];
            yn[j] = v;
        }
#pragma unroll
        for (int j = 0; j < 10; j++) yr[j] = yn[j];
    }
}

// ---------------- Final: out[g] = sigmoid(gacc[g] / max(count,1)) ----------------
__global__ void k4_final(const float* __restrict__ gacc, const int* __restrict__ node_graph,
                         float* __restrict__ out, int N, int G) {
    int g = blockIdx.x * blockDim.x + threadIdx.x;
    if (g >= G) return;
    // count of nodes with node_graph == g via two binary searches (sorted input)
    int lo = 0, hi = N;
    while (lo < hi) { int m = (lo + hi) >> 1; if (node_graph[m] < g) lo = m + 1; else hi = m; }
    int lo2 = lo, hi2 = N;
    while (lo2 < hi2) { int m = (lo2 + hi2) >> 1; if (node_graph[m] <= g) lo2 = m + 1; else hi2 = m; }
    float c = (float)(hi2 - lo);
    if (c < 1.f) c = 1.f;
    float s = gacc[g] / c;
    out[g] = 1.f / (1.f + __expf(-s));
}

template<int PAD>
static void run_all(const float* h, const int* src, const int* dst, const int* ng,
                    const float* W1[5], const float* b1[5], const float* W2[5],
                    const float* b2[5], const float* l[5],
                    float* out, void* d_ws, int N, int E, int G, hipStream_t stream) {
    float* y   = (float*)d_ws;
    float* agg = y + (size_t)N * PAD;
    float* gacc = agg + (size_t)N * PAD;

    hipMemsetAsync(agg, 0, (size_t)N * PAD * sizeof(float), stream);
    hipMemsetAsync(gacc, 0, (size_t)G * sizeof(float), stream);

    k1_hw1<PAD><<<(N + 255) / 256, 256, 0, stream>>>(h, W1[0], y, N);
    for (int i = 0; i < 5; i++) {
        k2_edge<PAD><<<(E + 255) / 256, 256, 0, stream>>>(src, dst, y, agg, E);
        k3_node<PAD><<<(N + 255) / 256, 256, 0, stream>>>(
            y, agg, b1[i], W2[i], b2[i], l[i],
            i < 4 ? W1[i + 1] : nullptr, ng, gacc, N, i == 4 ? 1 : 0);
    }
    k4_final<<<(G + 255) / 256, 256, 0, stream>>>(gacc, ng, out, N, G);
}

extern "C" void kernel_launch(void* const* d_in, const int* in_sizes, int n_in,
                              void* d_out, int out_size, void* d_ws, size_t ws_size,
                              hipStream_t stream) {
    const float* h  = (const float*)d_in[0];
    const int* src  = (const int*)d_in[1];
    const int* dst  = (const int*)d_in[2];
    const int* ng   = (const int*)d_in[3];
    int N = in_sizes[3];
    int E = in_sizes[1];
    int G = out_size;

    const float* W1[5]; const float* b1[5]; const float* W2[5]; const float* b2[5]; const float* l[5];
    for (int i = 0; i < 5; i++) {
        W1[i] = (const float*)d_in[4 + i * 5 + 0];
        b1[i] = (const float*)d_in[4 + i * 5 + 1];
        W2[i] = (const float*)d_in[4 + i * 5 + 2];
        b2[i] = (const float*)d_in[4 + i * 5 + 3];
        l[i]  = (const float*)d_in[4 + i * 5 + 4];
    }
    float* out = (float*)d_out;

    size_t need16 = (2ull * N * 16 + G) * sizeof(float);
    if (ws_size >= need16) {
        run_all<16>(h, src, dst, ng, W1, b1, W2, b2, l, out, d_ws, N, E, G, stream);
    } else {
        run_all<12>(h, src, dst, ng, W1, b1, W2, b2, l, out, d_ws, N, E, G, stream);
    }
}

// Round 2
// 4378.960 us; speedup vs baseline: 10.2020x; 10.2020x over previous
//
#include <hip/hip_runtime.h>

// GIN: 5 layers, DIM=10. Identity: (x+agg)@W1 = x@W1 + segsum((x@W1)[src]).
// R2: dst-CSR counting sort once per call; per-layer fused gather+MLP with
// register accumulation (no f32 atomics in the hot phase). y rows padded to
// 16 floats (64B) so each random gather is one cache line.

// ---------------- Layer-1: y = h @ W1_1   (h:[N,64], W1:[64,10]) ----------------
template<int PAD>
__global__ void k1_hw1(const float* __restrict__ h, const float* __restrict__ W1,
                       float* __restrict__ y, int N) {
    __shared__ float sW[640];
    for (int i = threadIdx.x; i < 640; i += blockDim.x) sW[i] = W1[i];
    __syncthreads();
    int n = blockIdx.x * blockDim.x + threadIdx.x;
    if (n >= N) return;
    const float* hr = h + (size_t)n * 64;
    float acc[10];
#pragma unroll
    for (int j = 0; j < 10; j++) acc[j] = 0.f;
#pragma unroll 4
    for (int k = 0; k < 64; k += 4) {
        float4 hv = *(const float4*)(hr + k);
#pragma unroll
        for (int j = 0; j < 10; j++) {
            acc[j] += hv.x * sW[(k + 0) * 10 + j];
            acc[j] += hv.y * sW[(k + 1) * 10 + j];
            acc[j] += hv.z * sW[(k + 2) * 10 + j];
            acc[j] += hv.w * sW[(k + 3) * 10 + j];
        }
    }
    float* yr = y + (size_t)n * PAD;
#pragma unroll
    for (int j = 0; j < 10; j++) yr[j] = acc[j];
}

// ---------------- CSR build: histogram / scan / scatter ----------------
__global__ void k_hist(const int* __restrict__ dst, unsigned* __restrict__ cnt, int E) {
    int stride = gridDim.x * blockDim.x;
    for (int e = blockIdx.x * blockDim.x + threadIdx.x; e < E; e += stride)
        atomicAdd(&cnt[dst[e]], 1u);
}

// scan1: per-block (1024 elems) exclusive scan in place, emit block totals
__global__ void k_scan1(unsigned* __restrict__ data, unsigned* __restrict__ bsums, int N) {
    __shared__ unsigned tmp[1024];
    int t = threadIdx.x;
    int idx = blockIdx.x * 1024 + t;
    unsigned v = (idx < N) ? data[idx] : 0u;
    tmp[t] = v;
    __syncthreads();
    for (int off = 1; off < 1024; off <<= 1) {
        unsigned u = (t >= off) ? tmp[t - off] : 0u;
        __syncthreads();
        tmp[t] += u;
        __syncthreads();
    }
    if (idx < N) data[idx] = tmp[t] - v;           // exclusive within block
    if (t == 1023) bsums[blockIdx.x] = tmp[1023];  // block total
}

// scan2: exclusive scan of block totals (<=1024 blocks), single block
__global__ void k_scan2(unsigned* __restrict__ bsums, int nb) {
    __shared__ unsigned tmp[1024];
    int t = threadIdx.x;
    unsigned v = (t < nb) ? bsums[t] : 0u;
    tmp[t] = v;
    __syncthreads();
    for (int off = 1; off < 1024; off <<= 1) {
        unsigned u = (t >= off) ? tmp[t - off] : 0u;
        __syncthreads();
        tmp[t] += u;
        __syncthreads();
    }
    if (t < nb) bsums[t] = tmp[t] - v;
}

// scan3: add block offsets; duplicate into cursor
__global__ void k_scan3(unsigned* __restrict__ data, const unsigned* __restrict__ bsums,
                        unsigned* __restrict__ cursor, int N) {
    int n = blockIdx.x * blockDim.x + threadIdx.x;
    if (n >= N) return;
    unsigned v = data[n] + bsums[n >> 10];
    data[n] = v;
    cursor[n] = v;
}

__global__ void k_scatter(const int* __restrict__ src, const int* __restrict__ dst,
                          unsigned* __restrict__ cursor, unsigned* __restrict__ edges, int E) {
    int stride = gridDim.x * blockDim.x;
    for (int e = blockIdx.x * blockDim.x + threadIdx.x; e < E; e += stride) {
        unsigned pos = atomicAdd(&cursor[dst[e]], 1u);
        edges[pos] = (unsigned)src[e];
    }
}

// ------- Fused layer: acc = y[n] + sum_{in-edges} y[src]; z=relu(acc+b1);
//         x=relu(z@W2+b2); p=x.l -> gacc; yout = x@W1_next -------
__global__ __launch_bounds__(256) void k_layer(
        const float* __restrict__ yin, float* __restrict__ yout,
        const unsigned* __restrict__ row_start, const unsigned* __restrict__ edges,
        const float* __restrict__ b1, const float* __restrict__ W2,
        const float* __restrict__ b2, const float* __restrict__ l,
        const float* __restrict__ W1n,
        const int* __restrict__ node_graph, float* __restrict__ gacc,
        int N, int E, int last) {
    __shared__ float sW2[100], sW1[100], sb1[10], sb2[10], sl[10];
    int t = threadIdx.x;
    if (t < 100) sW2[t] = W2[t];
    if (!last && t >= 128 && t < 228) sW1[t - 128] = W1n[t - 128];
    if (t < 10) { sb1[t] = b1[t]; sb2[t] = b2[t]; sl[t] = l[t]; }
    __syncthreads();
    int n = blockIdx.x * 256 + t;
    bool valid = n < N;
    int nc = valid ? n : (N - 1);

    const float* yr = yin + (size_t)nc * 16;
    float4 a = *(const float4*)yr;
    float4 b = *(const float4*)(yr + 4);
    float2 c = *(const float2*)(yr + 8);
    float acc[10] = {a.x, a.y, a.z, a.w, b.x, b.y, b.z, b.w, c.x, c.y};

    if (valid) {
        unsigned beg = row_start[n];
        unsigned end = (n + 1 < N) ? row_start[n + 1] : (unsigned)E;
        for (unsigned e = beg; e < end; ++e) {
            unsigned s = edges[e];
            const float* pr = yin + (size_t)s * 16;
            float4 pa = *(const float4*)pr;
            float4 pb = *(const float4*)(pr + 4);
            float2 pc = *(const float2*)(pr + 8);
            acc[0] += pa.x; acc[1] += pa.y; acc[2] += pa.z; acc[3] += pa.w;
            acc[4] += pb.x; acc[5] += pb.y; acc[6] += pb.z; acc[7] += pb.w;
            acc[8] += pc.x; acc[9] += pc.y;
        }
    }

    float z[10], x[10];
#pragma unroll
    for (int j = 0; j < 10; j++) {
        float v = acc[j] + sb1[j];
        z[j] = v > 0.f ? v : 0.f;
    }
#pragma unroll
    for (int j = 0; j < 10; j++) {
        float v = sb2[j];
#pragma unroll
        for (int k = 0; k < 10; k++) v += z[k] * sW2[k * 10 + j];
        x[j] = v > 0.f ? v : 0.f;
    }
    float p = 0.f;
#pragma unroll
    for (int j = 0; j < 10; j++) p += x[j] * sl[j];
    if (!valid) p = 0.f;
    int g = node_graph[nc];

    int g0 = __shfl(g, 0);
    if (__all(g == g0)) {
#pragma unroll
        for (int off = 32; off > 0; off >>= 1) p += __shfl_down(p, off);
        if ((t & 63) == 0) unsafeAtomicAdd(&gacc[g0], p);
    } else {
        if (valid) unsafeAtomicAdd(&gacc[g], p);
    }

    if (!last && valid) {
        float yn[10];
#pragma unroll
        for (int j = 0; j < 10; j++) {
            float v = 0.f;
#pragma unroll
            for (int k = 0; k < 10; k++) v += x[k] * sW1[k * 10 + j];
            yn[j] = v;
        }
        float* yo = yout + (size_t)n * 16;
#pragma unroll
        for (int j = 0; j < 10; j++) yo[j] = yn[j];
    }
}

// ---------------- Final: out[g] = sigmoid(gacc[g] / max(count,1)) ----------------
__global__ void k4_final(const float* __restrict__ gacc, const int* __restrict__ node_graph,
                         float* __restrict__ out, int N, int G) {
    int g = blockIdx.x * blockDim.x + threadIdx.x;
    if (g >= G) return;
    int lo = 0, hi = N;
    while (lo < hi) { int m = (lo + hi) >> 1; if (node_graph[m] < g) lo = m + 1; else hi = m; }
    int lo2 = lo, hi2 = N;
    while (lo2 < hi2) { int m = (lo2 + hi2) >> 1; if (node_graph[m] <= g) lo2 = m + 1; else hi2 = m; }
    float c = (float)(hi2 - lo);
    if (c < 1.f) c = 1.f;
    float s = gacc[g] / c;
    out[g] = 1.f / (1.f + __expf(-s));
}

// ================= fallback (R1 atomic path) for small workspace =================
template<int PAD>
__global__ void k2_edge(const int* __restrict__ src, const int* __restrict__ dst,
                        const float* __restrict__ y, float* __restrict__ agg, int E) {
    int e = blockIdx.x * blockDim.x + threadIdx.x;
    if (e >= E) return;
    size_t s = (size_t)src[e] * PAD;
    size_t d = (size_t)dst[e] * PAD;
    float4 a = *(const float4*)(y + s);
    float4 b = *(const float4*)(y + s + 4);
    float2 c = *(const float2*)(y + s + 8);
    float* ag = agg + d;
    unsafeAtomicAdd(ag + 0, a.x); unsafeAtomicAdd(ag + 1, a.y);
    unsafeAtomicAdd(ag + 2, a.z); unsafeAtomicAdd(ag + 3, a.w);
    unsafeAtomicAdd(ag + 4, b.x); unsafeAtomicAdd(ag + 5, b.y);
    unsafeAtomicAdd(ag + 6, b.z); unsafeAtomicAdd(ag + 7, b.w);
    unsafeAtomicAdd(ag + 8, c.x); unsafeAtomicAdd(ag + 9, c.y);
}

template<int PAD>
__global__ void k3_node(float* __restrict__ y, float* __restrict__ agg,
                        const float* __restrict__ b1, const float* __restrict__ W2,
                        const float* __restrict__ b2, const float* __restrict__ l,
                        const float* __restrict__ W1n,
                        const int* __restrict__ node_graph, float* __restrict__ gacc,
                        int N, int last) {
    __shared__ float sW2[100], sW1[100], sb1[10], sb2[10], sl[10];
    int t = threadIdx.x;
    if (t < 100) sW2[t] = W2[t];
    if (!last && t >= 128 && t < 228) sW1[t - 128] = W1n[t - 128];
    if (t < 10) { sb1[t] = b1[t]; sb2[t] = b2[t]; sl[t] = l[t]; }
    __syncthreads();
    int n = blockIdx.x * blockDim.x + t;
    bool valid = n < N;
    int nc = valid ? n : (N - 1);
    float* yr = y + (size_t)nc * PAD;
    float* ar = agg + (size_t)nc * PAD;
    float z[10], x[10];
#pragma unroll
    for (int j = 0; j < 10; j++) {
        float v = yr[j] + ar[j] + sb1[j];
        z[j] = v > 0.f ? v : 0.f;
    }
    if (valid) {
#pragma unroll
        for (int j = 0; j < 10; j++) ar[j] = 0.f;
    }
#pragma unroll
    for (int j = 0; j < 10; j++) {
        float v = sb2[j];
#pragma unroll
        for (int k = 0; k < 10; k++) v += z[k] * sW2[k * 10 + j];
        x[j] = v > 0.f ? v : 0.f;
    }
    float p = 0.f;
#pragma unroll
    for (int j = 0; j < 10; j++) p += x[j] * sl[j];
    if (!valid) p = 0.f;
    int g = node_graph[nc];
    int g0 = __shfl(g, 0);
    if (__all(g == g0)) {
#pragma unroll
        for (int off = 32; off > 0; off >>= 1) p += __shfl_down(p, off);
        if ((t & 63) == 0) unsafeAtomicAdd(&gacc[g0], p);
    } else {
        if (valid) unsafeAtomicAdd(&gacc[g], p);
    }
    if (!last && valid) {
        float yn[10];
#pragma unroll
        for (int j = 0; j < 10; j++) {
            float v = 0.f;
#pragma unroll
            for (int k = 0; k < 10; k++) v += x[k] * sW1[k * 10 + j];
            yn[j] = v;
        }
#pragma unroll
        for (int j = 0; j < 10; j++) yr[j] = yn[j];
    }
}

extern "C" void kernel_launch(void* const* d_in, const int* in_sizes, int n_in,
                              void* d_out, int out_size, void* d_ws, size_t ws_size,
                              hipStream_t stream) {
    const float* h  = (const float*)d_in[0];
    const int* src  = (const int*)d_in[1];
    const int* dst  = (const int*)d_in[2];
    const int* ng   = (const int*)d_in[3];
    int N = in_sizes[3];
    int E = in_sizes[1];
    int G = out_size;

    const float* W1[5]; const float* b1[5]; const float* W2[5]; const float* b2[5]; const float* l[5];
    for (int i = 0; i < 5; i++) {
        W1[i] = (const float*)d_in[4 + i * 5 + 0];
        b1[i] = (const float*)d_in[4 + i * 5 + 1];
        W2[i] = (const float*)d_in[4 + i * 5 + 2];
        b2[i] = (const float*)d_in[4 + i * 5 + 3];
        l[i]  = (const float*)d_in[4 + i * 5 + 4];
    }
    float* out = (float*)d_out;

    // CSR-path workspace layout (all 4-byte elements):
    //   y0[N*16] | y1[N*16] | row_start[N] | cursor[N] | bsums[1024] | edges[E] | gacc[G]
    size_t need_csr = ((size_t)N * 32 + 2ull * N + 1024 + (size_t)E + G) * 4;

    if (ws_size >= need_csr) {
        float* y0 = (float*)d_ws;
        float* y1 = y0 + (size_t)N * 16;
        unsigned* row_start = (unsigned*)(y1 + (size_t)N * 16);
        unsigned* cursor = row_start + N;
        unsigned* bsums = cursor + N;
        unsigned* edges = bsums + 1024;
        float* gacc = (float*)(edges + E);

        hipMemsetAsync(row_start, 0, (size_t)N * 4, stream);
        hipMemsetAsync(gacc, 0, (size_t)G * 4, stream);

        k1_hw1<16><<<(N + 255) / 256, 256, 0, stream>>>(h, W1[0], y0, N);

        k_hist<<<2048, 256, 0, stream>>>(dst, row_start, E);
        int nb = (N + 1023) / 1024;  // 489 <= 1024
        k_scan1<<<nb, 1024, 0, stream>>>(row_start, bsums, N);
        k_scan2<<<1, 1024, 0, stream>>>(bsums, nb);
        k_scan3<<<(N + 255) / 256, 256, 0, stream>>>(row_start, bsums, cursor, N);
        k_scatter<<<2048, 256, 0, stream>>>(src, dst, cursor, edges, E);

        float* ybuf[2] = {y0, y1};
        for (int i = 0; i < 5; i++) {
            k_layer<<<(N + 255) / 256, 256, 0, stream>>>(
                ybuf[i & 1], ybuf[(i + 1) & 1], row_start, edges,
                b1[i], W2[i], b2[i], l[i], i < 4 ? W1[i + 1] : nullptr,
                ng, gacc, N, E, i == 4 ? 1 : 0);
        }
        k4_final<<<(G + 255) / 256, 256, 0, stream>>>(gacc, ng, out, N, G);
    } else {
        // fallback: R1 atomic path
        const int PAD = 12;
        float* y   = (float*)d_ws;
        float* agg = y + (size_t)N * PAD;
        float* gacc = agg + (size_t)N * PAD;
        hipMemsetAsync(agg, 0, (size_t)N * PAD * sizeof(float), stream);
        hipMemsetAsync(gacc, 0, (size_t)G * sizeof(float), stream);
        k1_hw1<PAD><<<(N + 255) / 256, 256, 0, stream>>>(h, W1[0], y, N);
        for (int i = 0; i < 5; i++) {
            k2_edge<PAD><<<(E + 255) / 256, 256, 0, stream>>>(src, dst, y, agg, E);
            k3_node<PAD><<<(N + 255) / 256, 256, 0, stream>>>(
                y, agg, b1[i], W2[i], b2[i], l[i],
                i < 4 ? W1[i + 1] : nullptr, ng, gacc, N, i == 4 ? 1 : 0);
        }
        k4_final<<<(G + 255) / 256, 256, 0, stream>>>(gacc, ng, out, N, G);
    }
}